// Round 6
// baseline (654.830 us; speedup 1.0000x reference)
//
#include <hip/hip_runtime.h>

#define T_STEPS 500
#define BATCH   2048
#define NIN     12
#define NL1     38
#define NL2     7

// fp32 I/O, FLOAT64 internal math — emulates a numpy float64 recompute of the
// scan exactly (inputs promoted f32->f64 exactly; all ops f64):
//   - cur1 = x . W1[row]: sequential f64 FMA ascending k (BLAS dgemm order)
//   - elementwise: ((beta1*mem1) + cur1) + (V*spk1), each f64 op rounded.
//     V*spk1 realized as (sp ? vj : vj*0.0) — bit-exact incl. signed zero.
//   - mem - spk*thr realized as (sp ? mem-thr : mem) — bit-exact: spk=1 gives
//     rn(mem-thr) (same op as the compare operand d), spk=0 gives mem
//     (matching mem-(+0) == mem for all values incl. -0).
//   - cur2: spikes in {0,1} -> sequential ascending-j selected adds, realized
//     as cur2 = fma(bsel, w2r[j], cur2), bsel in {0.0,1.0}. fma(1,w,c)=rn(w+c);
//     fma(0,w,c)=rn(±0+c)=c (cur2 is never -0 along the chain: RN exact
//     cancellation yields +0, and ±0 + +0 = +0). Bit-exact.
//   - outputs cast f64 -> f32 on store (matches ref cast for comparison)
//
// Schedule (values unchanged):
//   - layer 2 skewed one step: iteration t computes L1(t) and L2(t-1); the
//     38-deep cur2 chain interleaves with cur1's 12-deep chain. Epilogue
//     finishes L2(T-1). Iteration 0 runs a harmless all-zero L2(-1).
//   - UNIFIED membrane update: per-lane beta/cur/vsel fold the L1 and L2
//     updates + stores into one set of wave ops (halves update+store issue).
//   - x prefetched 2 steps ahead as 3x float4 (covers ~900cy HBM latency).
//   - b pinned wave-uniform via readfirstlane: x addresses become scalar, so
//     the prefetch can use the SMEM pipe / SGPR buffers (frees ~36 VGPRs).
//   - bounds checks hoisted: all store offsets are affine in t; one
//     precomputed safeAll predicate replaces 2 v_cmp per iteration.
//     (audited: safeAll is TRUE at exact output size — max L2 offset
//      92,159,999 < 92,160,000; does not silently disable stores)
//   - NONTEMPORAL output stores: 369 MB written, never re-read in-kernel ->
//     nt hint stops the write stream from polluting L2/L3 (results identical).
// One wave per batch element: lanes 0..37 = layer-1 neurons, 38..44 = layer-2.
__global__ __launch_bounds__(256) void snn_kernel(
    const float* __restrict__ x,  const float* __restrict__ W1,
    const float* __restrict__ V,  const float* __restrict__ W2,
    const float* __restrict__ b1p, const float* __restrict__ b2p,
    const float* __restrict__ thrp, float* __restrict__ out, int out_n)
{
#pragma clang fp contract(off)
    const int tid  = threadIdx.x;
    const int lane = tid & 63;
    const int wave = tid >> 6;
    // b is wave-uniform by construction; readfirstlane makes that visible to
    // the compiler (SGPR), scalarizing the x-address chain below.
    const int b    = __builtin_amdgcn_readfirstlane(blockIdx.x * 4 + wave);

    const double beta1 = (double)b1p[0];
    const double beta2 = (double)b2p[0];
    const double thr   = (double)thrp[0];

    const bool isL1 = lane < NL1;
    const bool isL2 = (lane >= NL1) && (lane < NL1 + NL2);

    // layer-1 per-lane weights (f32 -> f64, exact)
    double w1r[NIN];
    #pragma unroll
    for (int i = 0; i < NIN; ++i)
        w1r[i] = isL1 ? (double)W1[lane * NIN + i] : 0.0;
    const double vj  = isL1 ? (double)V[lane] : 0.0;
    const double vj0 = vj * 0.0;           // signed zero matching V*0.0

    // layer-2 per-lane weight row (k=0 fallback keeps address in-bounds;
    // idle lanes compute garbage that is never stored or balloted into cur2)
    double w2r[NL1];
    {
        const int k = isL2 ? (lane - NL1) : 0;
        #pragma unroll
        for (int j = 0; j < NL1; ++j)
            w2r[j] = (double)W2[k * NL1 + j];
    }

    const double beta_l = isL1 ? beta1 : beta2;

    const int S1   = T_STEPS * BATCH * NL1;
    const int S2   = T_STEPS * BATCH * NL2;
    const int str1 = BATCH * NL1;
    const int str2 = BATCH * NL2;

    // per-lane store offsets; L2 lanes lag one step (skew): at iteration t the
    // L2 slot is (t-1), guarded by t>0. Idle lanes: stride 0, never store.
    int os, om, stride;
    if (isL1) {
        os = b * NL1 + lane;                 om = os + S1; stride = str1;
    } else if (isL2) {
        os = 2 * S1 + b * NL2 + (lane - NL1) - str2;
        om = os + S2;                        stride = str2;
    } else {
        os = 0; om = 0; stride = 0;
    }

    // Hoisted range check: the largest offset this lane ever stores is
    // bounded by om + T_STEPS*stride (om > os always). One check, loop-free.
    const bool safeAll = ((long long)om + (long long)T_STEPS * stride) < (long long)out_n;

    // x as float4: NIN=12 floats = 3 quads; 48B per element, 16B-aligned.
    const float4* xq   = reinterpret_cast<const float4*>(x) + (size_t)b * (NIN / 4);
    const int     QSTEP = BATCH * (NIN / 4);

    // 2-deep prefetch pipeline: a* = x(t), c* = x(t+1); loop loads x(t+2).
    float4 a0 = xq[0],         a1 = xq[1],         a2 = xq[2];
    float4 c0 = xq[QSTEP + 0], c1 = xq[QSTEP + 1], c2 = xq[QSTEP + 2];
    const float4* xn = xq + 2 * QSTEP;     // points at x(t+2)

    double mem = 0.0;
    bool sp_prev = false;
    unsigned long long mask_prev = 0ull;

    #pragma unroll 2
    for (int t = 0; t < T_STEPS; ++t) {
        // ---- prefetch x(t+2); tail re-reads an in-bounds earlier slice ----
        const float4* p = (t + 2 < T_STEPS) ? xn : (xn - 2 * QSTEP);
        const float4 n0 = p[0], n1 = p[1], n2 = p[2];
        xn += QSTEP;

        // ---- cur2 for step t-1 (wave-uniform mask -> scalar selects) ----
        double cur2 = 0.0;
        #pragma unroll
        for (int j = 0; j < NL1; ++j) {
            const double bsel = ((mask_prev >> j) & 1ull) ? 1.0 : 0.0;
            cur2 = __builtin_fma(bsel, w2r[j], cur2);
        }

        // ---- cur1 for step t from x(t) ----
        const float xf[NIN] = { a0.x, a0.y, a0.z, a0.w,
                                a1.x, a1.y, a1.z, a1.w,
                                a2.x, a2.y, a2.z, a2.w };
        double cur1 = 0.0;
        #pragma unroll
        for (int i = 0; i < NIN; ++i)
            cur1 = __builtin_fma((double)xf[i], w1r[i], cur1);

        // ---- unified membrane update (L1 @ t, L2 @ t-1) ----
        const double cur  = isL1 ? cur1 : cur2;
        const double vsel = sp_prev ? vj : vj0;     // +0.0 on L2/idle lanes
        mem = ((beta_l * mem) + cur) + vsel;
        const double d = mem - thr;
        const bool sp  = d > 0.0;
        mem = sp ? d : mem;
        sp_prev   = sp;
        mask_prev = __ballot(sp);      // bits >= NL1 never read by cur2

        const float sps  = sp ? 1.0f : 0.0f;
        const float memf = (float)mem;
        const bool actp  = (isL1 | (isL2 & (t > 0))) & safeAll;
        if (actp) {
            __builtin_nontemporal_store(sps,  &out[os]);
            __builtin_nontemporal_store(memf, &out[om]);
        }
        os += stride; om += stride;

        // rotate prefetch buffers (unroll-2 elides the copies)
        a0 = c0; a1 = c1; a2 = c2;
        c0 = n0; c1 = n1; c2 = n2;
    }

    // ---- epilogue: layer 2 for step T-1 ----
    {
        double cur2 = 0.0;
        #pragma unroll
        for (int j = 0; j < NL1; ++j) {
            const double bsel = ((mask_prev >> j) & 1ull) ? 1.0 : 0.0;
            cur2 = __builtin_fma(bsel, w2r[j], cur2);
        }
        if (isL2 && safeAll) {
            double m2 = (beta2 * mem) + cur2;
            const double d2 = m2 - thr;
            const bool sp2 = d2 > 0.0;
            m2 = sp2 ? d2 : m2;
            __builtin_nontemporal_store(sp2 ? 1.0f : 0.0f, &out[os]);
            __builtin_nontemporal_store((float)m2,          &out[om]);
        }
    }
}

extern "C" void kernel_launch(void* const* d_in, const int* in_sizes, int n_in,
                              void* d_out, int out_size, void* d_ws, size_t ws_size,
                              hipStream_t stream) {
    // Default: dict order (x, W1, V, W2, beta1, beta2, threshold).
    const void* x   = d_in[0];
    const void* W1p = (n_in > 1) ? d_in[1] : d_in[0];
    const void* Vp  = (n_in > 2) ? d_in[2] : d_in[0];
    const void* W2p = (n_in > 3) ? d_in[3] : d_in[0];
    const void* b1  = (n_in > 4) ? d_in[4] : d_in[0];
    const void* b2  = (n_in > 5) ? d_in[5] : d_in[0];
    const void* th  = (n_in > 6) ? d_in[6] : d_in[0];

    // Size-based override (element counts), only replaces on exact match.
    {
        const void* sc[3] = {0, 0, 0};
        int ns = 0;
        for (int i = 0; i < n_in; ++i) {
            const int s = in_sizes[i];
            if      (s == T_STEPS * BATCH * NIN) x   = d_in[i];
            else if (s == NL1 * NIN)             W1p = d_in[i];
            else if (s == NL2 * NL1)             W2p = d_in[i];
            else if (s == NL1)                   Vp  = d_in[i];
            else if (s == 1 && ns < 3)           sc[ns++] = d_in[i];
        }
        if (ns == 3) { b1 = sc[0]; b2 = sc[1]; th = sc[2]; }
    }

    snn_kernel<<<BATCH / 4, 256, 0, stream>>>(
        (const float*)x, (const float*)W1p, (const float*)Vp, (const float*)W2p,
        (const float*)b1, (const float*)b2, (const float*)th,
        (float*)d_out, out_size);
}